// Round 4
// baseline (334.653 us; speedup 1.0000x reference)
//
#include <hip/hip_runtime.h>
#include <hip/hip_bf16.h>

// Problem: B=4, L=2048, C=1024, H=16, D=64, M=B*L=8192. I/O f32.
// Internal: bf16 MFMA, f32 accumulate. Verified absmax 9.8e-4 (thr 4.04e-3).
// R13: attn LDS-pipe relief. R12 analysis: LDS pipe is the most-loaded
//   resource (18 b128 ops/step/wave, 4 waves re-read identical K/V tiles;
//   ~3456 cyc/step/CU vs MFMA 2560). K's A-frag needs a per-lane row
//   permutation (prow) that LDS staging can't exploit anyway, and K is
//   L2-resident (swizzle, proven FETCH 24.6MB). So: K fragments load
//   DIRECTLY from kb into registers, software-pipelined one ktile ahead
//   (2x4-frag ping-pong, +32 VGPR; per-wave ktile wall ~3000cy >> 200cy L2
//   latency — unlike R10's consume-immediately loads). V keeps the LDS
//   double-buffer (its layout transpose is real work). LDS ops/step 18->10.
//   Spill canary: WRITE_SIZE (16.4MB nominal). Rowsum stays in lacc MFMA
//   (R11: scalar chain -> scratch spill disaster).

typedef __attribute__((ext_vector_type(8))) short bf16x8;
typedef __attribute__((ext_vector_type(16))) float f32x16;

#define MAXLOG 4.60517018598809f   // ln(100)
#define LOG2E  1.4426950408889634f

__device__ __forceinline__ float bf2f(unsigned short u) {
    union { unsigned int i; float f; } v; v.i = ((unsigned int)u) << 16; return v.f;
}
__device__ __forceinline__ unsigned short f2bf(float f) {
    union { float f; unsigned int i; } v; v.f = f;
    unsigned int x = v.i;
    return (unsigned short)((x + 0x7FFFu + ((x >> 16) & 1u)) >> 16);  // RNE
}
__device__ __forceinline__ unsigned fbits(float f) {
    union { float f; unsigned u; } v; v.f = f; return v.u;
}
__device__ __forceinline__ bf16x8 pack8(const float* __restrict__ p) {
    float4 a = *(const float4*)p;
    float4 b = *(const float4*)(p + 4);
    bf16x8 r;
    r[0] = (short)f2bf(a.x); r[1] = (short)f2bf(a.y);
    r[2] = (short)f2bf(a.z); r[3] = (short)f2bf(a.w);
    r[4] = (short)f2bf(b.x); r[5] = (short)f2bf(b.y);
    r[6] = (short)f2bf(b.z); r[7] = (short)f2bf(b.w);
    return r;
}
__device__ __forceinline__ void gload_lds16(const void* g, void* l) {
    __builtin_amdgcn_global_load_lds((const __attribute__((address_space(1))) void*)g,
                                     (__attribute__((address_space(3))) void*)l, 16, 0, 0);
}

// ---------------------------------------- fused prep: casts + bias (1 kernel)
__global__ __launch_bounds__(256) void k_prep(
    const float* __restrict__ x, const float* __restrict__ Wqkv,
    const float* __restrict__ Wp, const float* __restrict__ qbia,
    const float* __restrict__ vbia,
    unsigned short* __restrict__ xb, unsigned short* __restrict__ Wqkvb,
    unsigned short* __restrict__ Wpb, float* __restrict__ bias3)
{
    int i = blockIdx.x * 256 + threadIdx.x;
    if (i < 1048576) {
        *(bf16x8*)&xb[(long)i * 8] = pack8(&x[(long)i * 8]);
    } else if (i < 1441792) {
        int j = i - 1048576;
        *(bf16x8*)&Wqkvb[(long)j * 8] = pack8(&Wqkv[(long)j * 8]);
    } else if (i < 1572864) {
        int j = i - 1441792;
        *(bf16x8*)&Wpb[(long)j * 8] = pack8(&Wp[(long)j * 8]);
    } else if (i < 1573248) {
        int j = (i - 1572864) * 8;
        for (int u = 0; u < 8; ++u) {
            int n = j + u;
            float v = 0.0f;
            if (n < 1024) v = qbia[n];
            else if (n >= 2048) v = vbia[n - 2048];
            bias3[n] = v;
        }
    }
}

// ------------------------- GEMM, B^T input, 32x32x16 MFMA, global_load_lds
template<bool OUT_F32>
__global__ __launch_bounds__(256) void k_gemm_lds(
    const unsigned short* __restrict__ A, const unsigned short* __restrict__ Bh,
    const float* __restrict__ bias, void* __restrict__ Cp, int N, int K)
{
    __shared__ unsigned short As[128 * 32];
    __shared__ unsigned short Bs[128 * 32];
    const int t = threadIdx.x, wave = t >> 6, lane = t & 63;
    const int m32 = lane & 31, half = lane >> 5;
    const int bm = blockIdx.x * 128, bn = blockIdx.y * 128;
    const int wr = (wave >> 1) * 64, wc = (wave & 1) * 64;
    f32x16 acc[2][2] = {};

    const int srow = lane >> 2;        // 0..15
    const int scol = (lane & 3) * 8;
    const int c0 = wave * 2, c1 = wave * 2 + 1;
    const long ga0 = (long)(bm + c0 * 16 + srow) * K + scol;
    const long ga1 = (long)(bm + c1 * 16 + srow) * K + scol;
    const long gb0 = (long)(bn + c0 * 16 + srow) * K + scol;
    const long gb1 = (long)(bn + c1 * 16 + srow) * K + scol;

    for (int kt = 0; kt < K; kt += 32) {
        __syncthreads();
        gload_lds16(&A[ga0 + kt], &As[c0 * 512]);
        gload_lds16(&A[ga1 + kt], &As[c1 * 512]);
        gload_lds16(&Bh[gb0 + kt], &Bs[c0 * 512]);
        gload_lds16(&Bh[gb1 + kt], &Bs[c1 * 512]);
        __syncthreads();
        bf16x8 af[2][2], bfr[2][2];
        for (int mt = 0; mt < 2; ++mt)
            for (int f = 0; f < 2; ++f)
                af[mt][f] = *(const bf16x8*)&As[(wr + mt * 32 + m32) * 32 + f * 16 + half * 8];
        for (int nt = 0; nt < 2; ++nt)
            for (int f = 0; f < 2; ++f)
                bfr[nt][f] = *(const bf16x8*)&Bs[(wc + nt * 32 + m32) * 32 + f * 16 + half * 8];
        for (int f = 0; f < 2; ++f)
            for (int mt = 0; mt < 2; ++mt)
                for (int nt = 0; nt < 2; ++nt)
                    acc[mt][nt] = __builtin_amdgcn_mfma_f32_32x32x16_bf16(
                        af[mt][f], bfr[nt][f], acc[mt][nt], 0, 0, 0);
    }
    // epilogue: 32x32 C/D layout col=lane&31, row=(r&3)+8*(r>>2)+4*half
    for (int mt = 0; mt < 2; ++mt)
        for (int nt = 0; nt < 2; ++nt) {
            int gn = bn + wc + nt * 32 + m32;
            float bv = bias[gn];
            for (int r = 0; r < 16; ++r) {
                int gm = bm + wr + mt * 32 + (r & 3) + 8 * (r >> 2) + 4 * half;
                float val = acc[mt][nt][r] + bv;
                if (OUT_F32) ((float*)Cp)[(long)gm * N + gn] = val;
                else ((unsigned short*)Cp)[(long)gm * N + gn] = f2bf(val);
            }
        }
}

// ------------------------- fused k L2-normalize + v transpose (one qkv pass)
__global__ __launch_bounds__(256) void k_prep_kv(
    const unsigned short* __restrict__ qkv, unsigned short* __restrict__ kb,
    unsigned short* __restrict__ vT)
{
    __shared__ unsigned short Vsh[64 * 72];
    const int t = threadIdx.x;
    const int bh = blockIdx.y, l0 = blockIdx.x * 64;
    const int h = bh & 15, b = bh >> 4;
    const int ll = t >> 2, c16 = (t & 3) * 16;
    const long rowbase = (long)(b * 2048 + l0 + ll) * 3072;

    {
        bf16x8 k0 = *(const bf16x8*)&qkv[rowbase + 1024 + h * 64 + c16];
        bf16x8 k1 = *(const bf16x8*)&qkv[rowbase + 1024 + h * 64 + c16 + 8];
        float e[16]; float ss = 0.f;
        for (int j = 0; j < 8; ++j) { e[j]     = bf2f((unsigned short)k0[j]); ss += e[j] * e[j]; }
        for (int j = 0; j < 8; ++j) { e[8 + j] = bf2f((unsigned short)k1[j]); ss += e[8 + j] * e[8 + j]; }
        ss += __shfl_xor(ss, 1, 64);
        ss += __shfl_xor(ss, 2, 64);
        float rs = 1.0f / fmaxf(sqrtf(ss), 1e-12f);
        bf16x8 o0, o1;
        for (int j = 0; j < 8; ++j) o0[j] = (short)f2bf(e[j] * rs);
        for (int j = 0; j < 8; ++j) o1[j] = (short)f2bf(e[8 + j] * rs);
        long dst = ((long)bh * 2048 + l0 + ll) * 64 + c16;
        *(bf16x8*)&kb[dst]     = o0;
        *(bf16x8*)&kb[dst + 8] = o1;
    }
    *(bf16x8*)&Vsh[ll * 72 + c16]     = *(const bf16x8*)&qkv[rowbase + 2048 + h * 64 + c16];
    *(bf16x8*)&Vsh[ll * 72 + c16 + 8] = *(const bf16x8*)&qkv[rowbase + 2048 + h * 64 + c16 + 8];
    __syncthreads();
    const int d = t >> 2, ls = (t & 3) * 16;
    unsigned short tmp[16];
    for (int j = 0; j < 16; ++j) tmp[j] = Vsh[(ls + j) * 72 + d];
    long dst = (long)(bh * 64 + d) * 2048 + l0 + ls;
    *(bf16x8*)&vT[dst]     = *(bf16x8*)&tmp[0];
    *(bf16x8*)&vT[dst + 8] = *(bf16x8*)&tmp[8];
}

// ------------------------------------------------------------ flash attention
// 32x32x16 MFMA, S^T form (key-permutation: P stays in registers).
// R13: K A-frags register-pipelined direct from kb (L2-resident); V keeps
// the LDS double-buffer. Rowsum in lacc MFMA accumulator.
__global__ __launch_bounds__(256, 4) void k_attn32(
    const unsigned short* __restrict__ qkv, const unsigned short* __restrict__ kb,
    const unsigned short* __restrict__ vT, const float* __restrict__ sml,
    unsigned short* __restrict__ attn)
{
    __shared__ unsigned short Vs[2][64 * 72];
    const int t = threadIdx.x, wave = t >> 6, lane = t & 63;
    const int m32 = lane & 31, half = lane >> 5;
    // XCD-chunked swizzle: hardware XCD = wg % 8; give each XCD 128
    // consecutive logical blocks = 8 (b,h) groups (K/V L2-resident).
    const int wg = blockIdx.x;
    const int logical = (wg & 7) * 128 + (wg >> 3);
    const int bh = logical >> 4, qblk = logical & 15;
    const int h = bh & 15, b = bh >> 4;
    const int q0 = qblk * 128 + wave * 32;
    const float scale = __expf(fminf(sml[h], MAXLOG));
    const float c2 = scale * LOG2E;   // shift for the (rare) large-scale path

    // permuted physical key row for the S^T A-frag (swap quads 1<->2, 5<->6)
    const int qd = m32 >> 2, lo = qd & 3;
    const int prow = ((((lo == 1) || (lo == 2)) ? (qd ^ 3) : qd) << 2) | (m32 & 3);

    // fused q load + L2-normalize; scale folded with LOG2E
    bf16x8 aq[4];
    {
        long base = (long)(b * 2048 + q0 + m32) * 3072 + h * 64;
        float e[32]; float ss = 0.f;
        for (int f = 0; f < 4; ++f) {
            aq[f] = *(const bf16x8*)&qkv[base + f * 16 + half * 8];
            for (int j = 0; j < 8; ++j) { float x = bf2f((unsigned short)aq[f][j]); e[f * 8 + j] = x; ss += x * x; }
        }
        ss += __shfl_xor(ss, 32, 64);
        float rs = (scale * LOG2E) / fmaxf(sqrtf(ss), 1e-12f);
        for (int f = 0; f < 4; ++f)
            for (int j = 0; j < 8; ++j) aq[f][j] = (short)f2bf(e[f * 8 + j] * rs);
    }

    f32x16 o0 = {}, o1 = {}, lacc = {};
    bf16x8 ones; for (int i = 0; i < 8; ++i) ones[i] = (short)0x3F80;
    const int sr = t >> 2, sc = (t & 3) * 16;
    const long kbase = (long)bh * 2048 * 64;
    const long vbase = (long)bh * 64 * 2048;
    // per-lane K fragment base: row perm + half-offset baked in
    const long kbR = kbase + (long)prow * 64 + half * 8;

// K fragments for one 32-key ktile straight from global (L2): 4 x b128.
#define LOADK4(P0, P1, P2, P3, BKT) \
    P0 = *(const bf16x8*)&kb[kbR + (long)(BKT) * 64];      \
    P1 = *(const bf16x8*)&kb[kbR + (long)(BKT) * 64 + 16]; \
    P2 = *(const bf16x8*)&kb[kbR + (long)(BKT) * 64 + 32]; \
    P3 = *(const bf16x8*)&kb[kbR + (long)(BKT) * 64 + 48];

#define LOADTV(kt) \
    vpA = *(const bf16x8*)&vT[vbase + (long)sr * 2048 + (kt) + sc];      \
    vpB = *(const bf16x8*)&vT[vbase + (long)sr * 2048 + (kt) + sc + 8];

#define STORETV(buf) \
    *(bf16x8*)&Vs[buf][sr * 72 + sc]     = vpA;  \
    *(bf16x8*)&Vs[buf][sr * 72 + sc + 8] = vpB;

// One 32-key ktile: QK^T (4 MFMA) -> exp2 -> pack -> PV (+rowsum MFMA).
#define ATTN_HALF(VS, KTOFF, K0, K1, K2, K3, SUB) \
    {                                                                                      \
        f32x16 s = {};                                                                     \
        s = __builtin_amdgcn_mfma_f32_32x32x16_bf16(K0, aq[0], s, 0, 0, 0);                \
        s = __builtin_amdgcn_mfma_f32_32x32x16_bf16(K1, aq[1], s, 0, 0, 0);                \
        s = __builtin_amdgcn_mfma_f32_32x32x16_bf16(K2, aq[2], s, 0, 0, 0);                \
        s = __builtin_amdgcn_mfma_f32_32x32x16_bf16(K3, aq[3], s, 0, 0, 0);                \
        unsigned pu[16];                                                                   \
        for (int j = 0; j < 16; ++j)                                                       \
            pu[j] = fbits(__builtin_amdgcn_exp2f(s[j] - (SUB)));                           \
        uint4 a0u, a1u;                                                                    \
        a0u.x = __builtin_amdgcn_perm(pu[1],  pu[0],  0x07060302u);                        \
        a0u.y = __builtin_amdgcn_perm(pu[3],  pu[2],  0x07060302u);                        \
        a0u.z = __builtin_amdgcn_perm(pu[5],  pu[4],  0x07060302u);                        \
        a0u.w = __builtin_amdgcn_perm(pu[7],  pu[6],  0x07060302u);                        \
        a1u.x = __builtin_amdgcn_perm(pu[9],  pu[8],  0x07060302u);                        \
        a1u.y = __builtin_amdgcn_perm(pu[11], pu[10], 0x07060302u);                        \
        a1u.z = __builtin_amdgcn_perm(pu[13], pu[12], 0x07060302u);                        \
        a1u.w = __builtin_amdgcn_perm(pu[15], pu[14], 0x07060302u);                        \
        bf16x8 ap0, ap1;                                                                   \
        __builtin_memcpy(&ap0, &a0u, 16); __builtin_memcpy(&ap1, &a1u, 16);                \
        for (int c = 0; c < 2; ++c) {                                                      \
            bf16x8 apc = c ? ap1 : ap0;                                                    \
            bf16x8 bv0 = *(const bf16x8*)&VS[m32 * 72        + (KTOFF) + c * 16 + half * 8]; \
            bf16x8 bv1 = *(const bf16x8*)&VS[(32 + m32) * 72 + (KTOFF) + c * 16 + half * 8]; \
            o0   = __builtin_amdgcn_mfma_f32_32x32x16_bf16(apc, bv0, o0, 0, 0, 0);         \
            o1   = __builtin_amdgcn_mfma_f32_32x32x16_bf16(apc, bv1, o1, 0, 0, 0);         \
            lacc = __builtin_amdgcn_mfma_f32_32x32x16_bf16(apc, ones, lacc, 0, 0, 0);      \
        }                                                                                  \
    }

// K-register ping-pong: kA holds the ktile being computed, kB the one in
// flight. Prefetch distance = 1 ktile (~3000 device-cy wave wall >> 200cy
// L2 latency). V double-buffer unchanged.
#define KLOOP(SUB) \
    for (int kt = 0; kt < 2048; kt += 128) {                       \
        LOADTV(kt + 64)                                            \
        LOADK4(kB0, kB1, kB2, kB3, kt + 32)                        \
        ATTN_HALF(Vs[0], 0,  kA0, kA1, kA2, kA3, SUB)              \
        LOADK4(kA0, kA1, kA2, kA3, kt + 64)                        \
        ATTN_HALF(Vs[0], 32, kB0, kB1, kB2, kB3, SUB)              \
        STORETV(1)                                                 \
        __syncthreads();                                           \
        const bool more = (kt + 128) < 2048;                       \
        if (more) { LOADTV(kt + 128) }                             \
        LOADK4(kB0, kB1, kB2, kB3, kt + 96)                        \
        ATTN_HALF(Vs[1], 0,  kA0, kA1, kA2, kA3, SUB)              \
        { const int pk = more ? kt + 128 : 0;                      \
          LOADK4(kA0, kA1, kA2, kA3, pk) }                         \
        ATTN_HALF(Vs[1], 32, kB0, kB1, kB2, kB3, SUB)              \
        if (more) {                                                \
            STORETV(0)                                             \
            __syncthreads();                                       \
        }                                                          \
    }

    bf16x8 kA0, kA1, kA2, kA3, kB0, kB1, kB2, kB3;
    bf16x8 vpA, vpB;
    LOADTV(0)
    LOADK4(kA0, kA1, kA2, kA3, 0)
    STORETV(0)
    __syncthreads();

    if (c2 < 30.0f) {      // wave-uniform; scale=4 here => fast path
        KLOOP(0.0f)        // s - 0.0f folds away: no per-score VALU shift
    } else {
        KLOOP(c2)          // overflow-safe general path
    }
#undef LOADK4
#undef LOADTV
#undef STORETV
#undef ATTN_HALF
#undef KLOOP

    // epilogue: divide by rowsum (lacc reg r matches o reg r), write attn[B,L,C]
    for (int r = 0; r < 16; ++r) {
        int m = (r & 3) + 8 * (r >> 2) + 4 * half;
        float inv = 1.0f / lacc[r];
        long dst = (long)(b * 2048 + q0 + m) * 1024 + h * 64;
        attn[dst + m32]      = f2bf(o0[r] * inv);
        attn[dst + 32 + m32] = f2bf(o1[r] * inv);
    }
}

// ---------------------------------------------------------------------------
extern "C" void kernel_launch(void* const* d_in, const int* in_sizes, int n_in,
                              void* d_out, int out_size, void* d_ws, size_t ws_size,
                              hipStream_t stream) {
    const float* x    = (const float*)d_in[0];
    const float* Wqkv = (const float*)d_in[1];
    const float* qbia = (const float*)d_in[2];
    const float* vbia = (const float*)d_in[3];
    const float* sml  = (const float*)d_in[4];
    const float* Wp   = (const float*)d_in[5];
    const float* bp   = (const float*)d_in[6];

    char* ws = (char*)d_ws;
    unsigned short* qkv   = (unsigned short*)ws;                    // [0, 50.33MB)
    unsigned short* kbuf  = (unsigned short*)(ws + 50331648);       // hosts Wqkvb first
    unsigned short* Wqkvb = kbuf;
    unsigned short* vT    = (unsigned short*)(ws + 67108864);       // hosts xb first
    unsigned short* xb    = vT;
    unsigned short* attnb = (unsigned short*)(ws + 83886080);
    float*          bias3 = (float*)(ws + 100663296);               // 12KB
    unsigned short* Wpb   = (unsigned short*)(ws + 100679680);      // 2MB
    float*          out   = (float*)d_out;

    hipLaunchKernelGGL(k_prep, dim3(6146), dim3(256), 0, stream,
                       x, Wqkv, Wp, qbia, vbia, xb, Wqkvb, Wpb, bias3);
    hipLaunchKernelGGL((k_gemm_lds<false>), dim3(64, 24), dim3(256), 0, stream,
                       xb, Wqkvb, bias3, (void*)qkv, 3072, 1024);
    hipLaunchKernelGGL(k_prep_kv, dim3(32, 64), dim3(256), 0, stream, qkv, kbuf, vT);
    hipLaunchKernelGGL(k_attn32, dim3(1024), dim3(256), 0, stream, qkv, kbuf, vT, sml, attnb);
    hipLaunchKernelGGL((k_gemm_lds<true>), dim3(64, 8), dim3(256), 0, stream,
                       attnb, Wpb, bp, (void*)out, 1024, 1024);
}

// Round 5
// 282.506 us; speedup vs baseline: 1.1846x; 1.1846x over previous
//
#include <hip/hip_runtime.h>
#include <hip/hip_bf16.h>

// Problem: B=4, L=2048, C=1024, H=16, D=64, M=B*L=8192. I/O f32.
// Internal: bf16 MFMA, f32 accumulate. Verified absmax 9.8e-4 (thr 4.04e-3).
// R14: amortize attn LDS reads — each wave computes 64 q-rows (two 32-q
//   groups) sharing the SAME K/V fragment registers for both groups' MFMAs.
//   LDS ops per unit work halve (R12 was LDS-top-pipe: 240cy LDS vs 160cy
//   MFMA per step; now 240 vs 320 -> MFMA-bound). Barrier/staging skeleton
//   is R12 verbatim (R13 lesson: __syncthreads drains vmcnt(0), so global
//   loads must issue early in the phase — LOADT does, K-direct didn't).
//   Cost: ~220 VGPR -> __launch_bounds__(256,2), occupancy ~25%; OK since
//   compute-per-staged-byte doubled. Spill canary: WRITE_SIZE 16.4MB.
//   Rowsum stays in lacc MFMA (R11: scalar chain -> spill disaster).

typedef __attribute__((ext_vector_type(8))) short bf16x8;
typedef __attribute__((ext_vector_type(16))) float f32x16;

#define MAXLOG 4.60517018598809f   // ln(100)
#define LOG2E  1.4426950408889634f

__device__ __forceinline__ float bf2f(unsigned short u) {
    union { unsigned int i; float f; } v; v.i = ((unsigned int)u) << 16; return v.f;
}
__device__ __forceinline__ unsigned short f2bf(float f) {
    union { float f; unsigned int i; } v; v.f = f;
    unsigned int x = v.i;
    return (unsigned short)((x + 0x7FFFu + ((x >> 16) & 1u)) >> 16);  // RNE
}
__device__ __forceinline__ unsigned fbits(float f) {
    union { float f; unsigned u; } v; v.f = f; return v.u;
}
__device__ __forceinline__ bf16x8 pack8(const float* __restrict__ p) {
    float4 a = *(const float4*)p;
    float4 b = *(const float4*)(p + 4);
    bf16x8 r;
    r[0] = (short)f2bf(a.x); r[1] = (short)f2bf(a.y);
    r[2] = (short)f2bf(a.z); r[3] = (short)f2bf(a.w);
    r[4] = (short)f2bf(b.x); r[5] = (short)f2bf(b.y);
    r[6] = (short)f2bf(b.z); r[7] = (short)f2bf(b.w);
    return r;
}
__device__ __forceinline__ void gload_lds16(const void* g, void* l) {
    __builtin_amdgcn_global_load_lds((const __attribute__((address_space(1))) void*)g,
                                     (__attribute__((address_space(3))) void*)l, 16, 0, 0);
}

// ---------------------------------------- fused prep: casts + bias (1 kernel)
__global__ __launch_bounds__(256) void k_prep(
    const float* __restrict__ x, const float* __restrict__ Wqkv,
    const float* __restrict__ Wp, const float* __restrict__ qbia,
    const float* __restrict__ vbia,
    unsigned short* __restrict__ xb, unsigned short* __restrict__ Wqkvb,
    unsigned short* __restrict__ Wpb, float* __restrict__ bias3)
{
    int i = blockIdx.x * 256 + threadIdx.x;
    if (i < 1048576) {
        *(bf16x8*)&xb[(long)i * 8] = pack8(&x[(long)i * 8]);
    } else if (i < 1441792) {
        int j = i - 1048576;
        *(bf16x8*)&Wqkvb[(long)j * 8] = pack8(&Wqkv[(long)j * 8]);
    } else if (i < 1572864) {
        int j = i - 1441792;
        *(bf16x8*)&Wpb[(long)j * 8] = pack8(&Wp[(long)j * 8]);
    } else if (i < 1573248) {
        int j = (i - 1572864) * 8;
        for (int u = 0; u < 8; ++u) {
            int n = j + u;
            float v = 0.0f;
            if (n < 1024) v = qbia[n];
            else if (n >= 2048) v = vbia[n - 2048];
            bias3[n] = v;
        }
    }
}

// ------------------------- GEMM, B^T input, 32x32x16 MFMA, global_load_lds
template<bool OUT_F32>
__global__ __launch_bounds__(256) void k_gemm_lds(
    const unsigned short* __restrict__ A, const unsigned short* __restrict__ Bh,
    const float* __restrict__ bias, void* __restrict__ Cp, int N, int K)
{
    __shared__ unsigned short As[128 * 32];
    __shared__ unsigned short Bs[128 * 32];
    const int t = threadIdx.x, wave = t >> 6, lane = t & 63;
    const int m32 = lane & 31, half = lane >> 5;
    const int bm = blockIdx.x * 128, bn = blockIdx.y * 128;
    const int wr = (wave >> 1) * 64, wc = (wave & 1) * 64;
    f32x16 acc[2][2] = {};

    const int srow = lane >> 2;        // 0..15
    const int scol = (lane & 3) * 8;
    const int c0 = wave * 2, c1 = wave * 2 + 1;
    const long ga0 = (long)(bm + c0 * 16 + srow) * K + scol;
    const long ga1 = (long)(bm + c1 * 16 + srow) * K + scol;
    const long gb0 = (long)(bn + c0 * 16 + srow) * K + scol;
    const long gb1 = (long)(bn + c1 * 16 + srow) * K + scol;

    for (int kt = 0; kt < K; kt += 32) {
        __syncthreads();
        gload_lds16(&A[ga0 + kt], &As[c0 * 512]);
        gload_lds16(&A[ga1 + kt], &As[c1 * 512]);
        gload_lds16(&Bh[gb0 + kt], &Bs[c0 * 512]);
        gload_lds16(&Bh[gb1 + kt], &Bs[c1 * 512]);
        __syncthreads();
        bf16x8 af[2][2], bfr[2][2];
        for (int mt = 0; mt < 2; ++mt)
            for (int f = 0; f < 2; ++f)
                af[mt][f] = *(const bf16x8*)&As[(wr + mt * 32 + m32) * 32 + f * 16 + half * 8];
        for (int nt = 0; nt < 2; ++nt)
            for (int f = 0; f < 2; ++f)
                bfr[nt][f] = *(const bf16x8*)&Bs[(wc + nt * 32 + m32) * 32 + f * 16 + half * 8];
        for (int f = 0; f < 2; ++f)
            for (int mt = 0; mt < 2; ++mt)
                for (int nt = 0; nt < 2; ++nt)
                    acc[mt][nt] = __builtin_amdgcn_mfma_f32_32x32x16_bf16(
                        af[mt][f], bfr[nt][f], acc[mt][nt], 0, 0, 0);
    }
    // epilogue: 32x32 C/D layout col=lane&31, row=(r&3)+8*(r>>2)+4*half
    for (int mt = 0; mt < 2; ++mt)
        for (int nt = 0; nt < 2; ++nt) {
            int gn = bn + wc + nt * 32 + m32;
            float bv = bias[gn];
            for (int r = 0; r < 16; ++r) {
                int gm = bm + wr + mt * 32 + (r & 3) + 8 * (r >> 2) + 4 * half;
                float val = acc[mt][nt][r] + bv;
                if (OUT_F32) ((float*)Cp)[(long)gm * N + gn] = val;
                else ((unsigned short*)Cp)[(long)gm * N + gn] = f2bf(val);
            }
        }
}

// ------------------------- fused k L2-normalize + v transpose (one qkv pass)
__global__ __launch_bounds__(256) void k_prep_kv(
    const unsigned short* __restrict__ qkv, unsigned short* __restrict__ kb,
    unsigned short* __restrict__ vT)
{
    __shared__ unsigned short Vsh[64 * 72];
    const int t = threadIdx.x;
    const int bh = blockIdx.y, l0 = blockIdx.x * 64;
    const int h = bh & 15, b = bh >> 4;
    const int ll = t >> 2, c16 = (t & 3) * 16;
    const long rowbase = (long)(b * 2048 + l0 + ll) * 3072;

    {
        bf16x8 k0 = *(const bf16x8*)&qkv[rowbase + 1024 + h * 64 + c16];
        bf16x8 k1 = *(const bf16x8*)&qkv[rowbase + 1024 + h * 64 + c16 + 8];
        float e[16]; float ss = 0.f;
        for (int j = 0; j < 8; ++j) { e[j]     = bf2f((unsigned short)k0[j]); ss += e[j] * e[j]; }
        for (int j = 0; j < 8; ++j) { e[8 + j] = bf2f((unsigned short)k1[j]); ss += e[8 + j] * e[8 + j]; }
        ss += __shfl_xor(ss, 1, 64);
        ss += __shfl_xor(ss, 2, 64);
        float rs = 1.0f / fmaxf(sqrtf(ss), 1e-12f);
        bf16x8 o0, o1;
        for (int j = 0; j < 8; ++j) o0[j] = (short)f2bf(e[j] * rs);
        for (int j = 0; j < 8; ++j) o1[j] = (short)f2bf(e[8 + j] * rs);
        long dst = ((long)bh * 2048 + l0 + ll) * 64 + c16;
        *(bf16x8*)&kb[dst]     = o0;
        *(bf16x8*)&kb[dst + 8] = o1;
    }
    *(bf16x8*)&Vsh[ll * 72 + c16]     = *(const bf16x8*)&qkv[rowbase + 2048 + h * 64 + c16];
    *(bf16x8*)&Vsh[ll * 72 + c16 + 8] = *(const bf16x8*)&qkv[rowbase + 2048 + h * 64 + c16 + 8];
    __syncthreads();
    const int d = t >> 2, ls = (t & 3) * 16;
    unsigned short tmp[16];
    for (int j = 0; j < 16; ++j) tmp[j] = Vsh[(ls + j) * 72 + d];
    long dst = (long)(bh * 64 + d) * 2048 + l0 + ls;
    *(bf16x8*)&vT[dst]     = *(bf16x8*)&tmp[0];
    *(bf16x8*)&vT[dst + 8] = *(bf16x8*)&tmp[8];
}

// ------------------------------------------------------------ flash attention
// 32x32x16 MFMA, S^T form (key-permutation: P stays in registers).
// R14: 64 q-rows per wave (two 32-q groups A/B sharing K/V fragment regs).
// Barrier/staging skeleton identical to R12. Rowsum in lacc MFMAs.
__global__ __launch_bounds__(256, 2) void k_attn32(
    const unsigned short* __restrict__ qkv, const unsigned short* __restrict__ kb,
    const unsigned short* __restrict__ vT, const float* __restrict__ sml,
    unsigned short* __restrict__ attn)
{
    __shared__ unsigned short Ks[2][64 * 72];
    __shared__ unsigned short Vs[2][64 * 72];
    const int t = threadIdx.x, wave = t >> 6, lane = t & 63;
    const int m32 = lane & 31, half = lane >> 5;
    // XCD-chunked swizzle: 512 blocks, 64 logical per XCD = 8 (b,h) groups
    // (4MB K/V = L2 size). Proven lever (R10: FETCH 139MB -> 24.6MB).
    const int wg = blockIdx.x;
    const int logical = (wg & 7) * 64 + (wg >> 3);
    const int bh = logical >> 3, qblk = logical & 7;
    const int h = bh & 15, b = bh >> 4;
    const int q0 = qblk * 256 + wave * 64;     // rows q0..q0+31 (A), q0+32..q0+63 (B)
    const float scale = __expf(fminf(sml[h], MAXLOG));
    const float c2 = scale * LOG2E;   // shift for the (rare) large-scale path

    // permuted physical key row for the S^T A-frag (swap quads 1<->2, 5<->6)
    const int qd = m32 >> 2, lo = qd & 3;
    const int prow = ((((lo == 1) || (lo == 2)) ? (qd ^ 3) : qd) << 2) | (m32 & 3);

    // fused q load + L2-normalize for both q-groups; scale folded with LOG2E
    bf16x8 aqA[4], aqB[4];
    {
        long base = (long)(b * 2048 + q0 + m32) * 3072 + h * 64;
        float e[32]; float ss = 0.f;
        for (int f = 0; f < 4; ++f) {
            aqA[f] = *(const bf16x8*)&qkv[base + f * 16 + half * 8];
            for (int j = 0; j < 8; ++j) { float x = bf2f((unsigned short)aqA[f][j]); e[f * 8 + j] = x; ss += x * x; }
        }
        ss += __shfl_xor(ss, 32, 64);
        float rs = (scale * LOG2E) / fmaxf(sqrtf(ss), 1e-12f);
        for (int f = 0; f < 4; ++f)
            for (int j = 0; j < 8; ++j) aqA[f][j] = (short)f2bf(e[f * 8 + j] * rs);
    }
    {
        long base = (long)(b * 2048 + q0 + 32 + m32) * 3072 + h * 64;
        float e[32]; float ss = 0.f;
        for (int f = 0; f < 4; ++f) {
            aqB[f] = *(const bf16x8*)&qkv[base + f * 16 + half * 8];
            for (int j = 0; j < 8; ++j) { float x = bf2f((unsigned short)aqB[f][j]); e[f * 8 + j] = x; ss += x * x; }
        }
        ss += __shfl_xor(ss, 32, 64);
        float rs = (scale * LOG2E) / fmaxf(sqrtf(ss), 1e-12f);
        for (int f = 0; f < 4; ++f)
            for (int j = 0; j < 8; ++j) aqB[f][j] = (short)f2bf(e[f * 8 + j] * rs);
    }

    f32x16 oA0 = {}, oA1 = {}, lA = {};
    f32x16 oB0 = {}, oB1 = {}, lB = {};
    bf16x8 ones; for (int i = 0; i < 8; ++i) ones[i] = (short)0x3F80;
    const int sr = t >> 2, sc = (t & 3) * 16;
    const long kbase = (long)bh * 2048 * 64;
    const long vbase = (long)bh * 64 * 2048;

#define LOADT(kt) \
    kpA = *(const bf16x8*)&kb[kbase + (long)((kt) + sr) * 64 + sc];      \
    kpB = *(const bf16x8*)&kb[kbase + (long)((kt) + sr) * 64 + sc + 8];  \
    vpA = *(const bf16x8*)&vT[vbase + (long)sr * 2048 + (kt) + sc];      \
    vpB = *(const bf16x8*)&vT[vbase + (long)sr * 2048 + (kt) + sc + 8];

#define STORET(buf) \
    *(bf16x8*)&Ks[buf][sr * 72 + sc]     = kpA;  \
    *(bf16x8*)&Ks[buf][sr * 72 + sc + 8] = kpB;  \
    *(bf16x8*)&Vs[buf][sr * 72 + sc]     = vpA;  \
    *(bf16x8*)&Vs[buf][sr * 72 + sc + 8] = vpB;

// QK^T + exp2 + pack for one q-group (AQ) into two packed A-frags (AP0,AP1)
#define SCORE(AQ, AP0, AP1, KF0, KF1, KF2, KF3, SUB) \
    {                                                                                      \
        f32x16 s = {};                                                                     \
        s = __builtin_amdgcn_mfma_f32_32x32x16_bf16(KF0, AQ[0], s, 0, 0, 0);               \
        s = __builtin_amdgcn_mfma_f32_32x32x16_bf16(KF1, AQ[1], s, 0, 0, 0);               \
        s = __builtin_amdgcn_mfma_f32_32x32x16_bf16(KF2, AQ[2], s, 0, 0, 0);               \
        s = __builtin_amdgcn_mfma_f32_32x32x16_bf16(KF3, AQ[3], s, 0, 0, 0);               \
        unsigned pu[16];                                                                   \
        for (int j = 0; j < 16; ++j)                                                       \
            pu[j] = fbits(__builtin_amdgcn_exp2f(s[j] - (SUB)));                           \
        uint4 a0u, a1u;                                                                    \
        a0u.x = __builtin_amdgcn_perm(pu[1],  pu[0],  0x07060302u);                        \
        a0u.y = __builtin_amdgcn_perm(pu[3],  pu[2],  0x07060302u);                        \
        a0u.z = __builtin_amdgcn_perm(pu[5],  pu[4],  0x07060302u);                        \
        a0u.w = __builtin_amdgcn_perm(pu[7],  pu[6],  0x07060302u);                        \
        a1u.x = __builtin_amdgcn_perm(pu[9],  pu[8],  0x07060302u);                        \
        a1u.y = __builtin_amdgcn_perm(pu[11], pu[10], 0x07060302u);                        \
        a1u.z = __builtin_amdgcn_perm(pu[13], pu[12], 0x07060302u);                        \
        a1u.w = __builtin_amdgcn_perm(pu[15], pu[14], 0x07060302u);                        \
        __builtin_memcpy(&AP0, &a0u, 16); __builtin_memcpy(&AP1, &a1u, 16);                \
    }

#define ATTN_STEP(KS, VS, SUB) \
    for (int ktile = 0; ktile < 2; ++ktile) {                                              \
        const unsigned short* krow = &KS[(ktile * 32 + prow) * 72 + half * 8];             \
        bf16x8 kf0 = *(const bf16x8*)&krow[0];                                             \
        bf16x8 kf1 = *(const bf16x8*)&krow[16];                                            \
        bf16x8 kf2 = *(const bf16x8*)&krow[32];                                            \
        bf16x8 kf3 = *(const bf16x8*)&krow[48];                                            \
        bf16x8 apA0, apA1, apB0, apB1;                                                     \
        SCORE(aqA, apA0, apA1, kf0, kf1, kf2, kf3, SUB)                                    \
        SCORE(aqB, apB0, apB1, kf0, kf1, kf2, kf3, SUB)                                    \
        for (int c = 0; c < 2; ++c) {                                                      \
            bf16x8 aA = c ? apA1 : apA0;                                                   \
            bf16x8 aB = c ? apB1 : apB0;                                                   \
            bf16x8 bv0 = *(const bf16x8*)&VS[m32 * 72        + ktile * 32 + c * 16 + half * 8]; \
            bf16x8 bv1 = *(const bf16x8*)&VS[(32 + m32) * 72 + ktile * 32 + c * 16 + half * 8]; \
            oA0 = __builtin_amdgcn_mfma_f32_32x32x16_bf16(aA, bv0, oA0, 0, 0, 0);          \
            oA1 = __builtin_amdgcn_mfma_f32_32x32x16_bf16(aA, bv1, oA1, 0, 0, 0);          \
            lA  = __builtin_amdgcn_mfma_f32_32x32x16_bf16(aA, ones, lA, 0, 0, 0);          \
            oB0 = __builtin_amdgcn_mfma_f32_32x32x16_bf16(aB, bv0, oB0, 0, 0, 0);          \
            oB1 = __builtin_amdgcn_mfma_f32_32x32x16_bf16(aB, bv1, oB1, 0, 0, 0);          \
            lB  = __builtin_amdgcn_mfma_f32_32x32x16_bf16(aB, ones, lB, 0, 0, 0);          \
        }                                                                                  \
    }

#define KLOOP(SUB) \
    for (int kt = 0; kt < 2048; kt += 128) {                 \
        LOADT(kt + 64)                                       \
        ATTN_STEP(Ks[0], Vs[0], SUB)                         \
        STORET(1)                                            \
        __syncthreads();                                     \
        const bool more = (kt + 128) < 2048;                 \
        if (more) { LOADT(kt + 128) }                        \
        ATTN_STEP(Ks[1], Vs[1], SUB)                         \
        if (more) {                                          \
            STORET(0)                                        \
            __syncthreads();                                 \
        }                                                    \
    }

    bf16x8 kpA, kpB, vpA, vpB;
    LOADT(0)
    STORET(0)
    __syncthreads();

    if (c2 < 30.0f) {      // wave-uniform; scale=4 here => fast path
        KLOOP(0.0f)        // s - 0.0f folds away: no per-score VALU shift
    } else {
        KLOOP(c2)          // overflow-safe general path
    }
#undef LOADT
#undef STORET
#undef SCORE
#undef ATTN_STEP
#undef KLOOP

    // epilogue: divide by rowsum (lacc reg r matches o reg r), write attn[B,L,C]
    for (int r = 0; r < 16; ++r) {
        int m = (r & 3) + 8 * (r >> 2) + 4 * half;
        float invA = 1.0f / lA[r];
        long dstA = (long)(b * 2048 + q0 + m) * 1024 + h * 64;
        attn[dstA + m32]      = f2bf(oA0[r] * invA);
        attn[dstA + 32 + m32] = f2bf(oA1[r] * invA);
        float invB = 1.0f / lB[r];
        long dstB = (long)(b * 2048 + q0 + 32 + m) * 1024 + h * 64;
        attn[dstB + m32]      = f2bf(oB0[r] * invB);
        attn[dstB + 32 + m32] = f2bf(oB1[r] * invB);
    }
}

// ---------------------------------------------------------------------------
extern "C" void kernel_launch(void* const* d_in, const int* in_sizes, int n_in,
                              void* d_out, int out_size, void* d_ws, size_t ws_size,
                              hipStream_t stream) {
    const float* x    = (const float*)d_in[0];
    const float* Wqkv = (const float*)d_in[1];
    const float* qbia = (const float*)d_in[2];
    const float* vbia = (const float*)d_in[3];
    const float* sml  = (const float*)d_in[4];
    const float* Wp   = (const float*)d_in[5];
    const float* bp   = (const float*)d_in[6];

    char* ws = (char*)d_ws;
    unsigned short* qkv   = (unsigned short*)ws;                    // [0, 50.33MB)
    unsigned short* kbuf  = (unsigned short*)(ws + 50331648);       // hosts Wqkvb first
    unsigned short* Wqkvb = kbuf;
    unsigned short* vT    = (unsigned short*)(ws + 67108864);       // hosts xb first
    unsigned short* xb    = vT;
    unsigned short* attnb = (unsigned short*)(ws + 83886080);
    float*          bias3 = (float*)(ws + 100663296);               // 12KB
    unsigned short* Wpb   = (unsigned short*)(ws + 100679680);      // 2MB
    float*          out   = (float*)d_out;

    hipLaunchKernelGGL(k_prep, dim3(6146), dim3(256), 0, stream,
                       x, Wqkv, Wp, qbia, vbia, xb, Wqkvb, Wpb, bias3);
    hipLaunchKernelGGL((k_gemm_lds<false>), dim3(64, 24), dim3(256), 0, stream,
                       xb, Wqkvb, bias3, (void*)qkv, 3072, 1024);
    hipLaunchKernelGGL(k_prep_kv, dim3(32, 64), dim3(256), 0, stream, qkv, kbuf, vT);
    hipLaunchKernelGGL(k_attn32, dim3(512), dim3(256), 0, stream, qkv, kbuf, vT, sml, attnb);
    hipLaunchKernelGGL((k_gemm_lds<true>), dim3(64, 8), dim3(256), 0, stream,
                       attnb, Wpb, bp, (void*)out, 1024, 1024);
}

// Round 6
// 274.953 us; speedup vs baseline: 1.2171x; 1.0275x over previous
//
#include <hip/hip_runtime.h>
#include <hip/hip_bf16.h>

// Problem: B=4, L=2048, C=1024, H=16, D=64, M=B*L=8192. I/O f32.
// Internal: bf16 MFMA, f32 accumulate. Verified absmax 9.8e-4 (thr 4.04e-3).
// R15: GEMM LDS bank-conflict fix. R14 counters: QKV GEMM 81us with
//   SQ_LDS_BANK_CONFLICT=1.89e7 (~12 extra cy per ds_read_b128 = ~30us of
//   LDS serialization; MfmaUtil only 27% vs 20.5us of MFMA work). Cause:
//   64B LDS rows concentrate fragment reads on 16/32 banks. Fix: XOR the
//   16B slot index with (row>>1)&3 on BOTH sides (rule 21 — staging's
//   per-lane GLOBAL source addr since global_load_lds dest is linear, and
//   the fragment-read col). Bank quad = (r&1)*4 + (f2h ^ ((r>>1)&3)) ->
//   all 32 banks, 8 lanes/quad, zero extra cycles. Coalescing unchanged
//   (same 64B line per 4-lane cluster, permuted within).
//   Attn kernel untouched (R14-verified 81us).

typedef __attribute__((ext_vector_type(8))) short bf16x8;
typedef __attribute__((ext_vector_type(16))) float f32x16;

#define MAXLOG 4.60517018598809f   // ln(100)
#define LOG2E  1.4426950408889634f

__device__ __forceinline__ float bf2f(unsigned short u) {
    union { unsigned int i; float f; } v; v.i = ((unsigned int)u) << 16; return v.f;
}
__device__ __forceinline__ unsigned short f2bf(float f) {
    union { float f; unsigned int i; } v; v.f = f;
    unsigned int x = v.i;
    return (unsigned short)((x + 0x7FFFu + ((x >> 16) & 1u)) >> 16);  // RNE
}
__device__ __forceinline__ unsigned fbits(float f) {
    union { float f; unsigned u; } v; v.f = f; return v.u;
}
__device__ __forceinline__ bf16x8 pack8(const float* __restrict__ p) {
    float4 a = *(const float4*)p;
    float4 b = *(const float4*)(p + 4);
    bf16x8 r;
    r[0] = (short)f2bf(a.x); r[1] = (short)f2bf(a.y);
    r[2] = (short)f2bf(a.z); r[3] = (short)f2bf(a.w);
    r[4] = (short)f2bf(b.x); r[5] = (short)f2bf(b.y);
    r[6] = (short)f2bf(b.z); r[7] = (short)f2bf(b.w);
    return r;
}
__device__ __forceinline__ void gload_lds16(const void* g, void* l) {
    __builtin_amdgcn_global_load_lds((const __attribute__((address_space(1))) void*)g,
                                     (__attribute__((address_space(3))) void*)l, 16, 0, 0);
}

// ---------------------------------------- fused prep: casts + bias (1 kernel)
__global__ __launch_bounds__(256) void k_prep(
    const float* __restrict__ x, const float* __restrict__ Wqkv,
    const float* __restrict__ Wp, const float* __restrict__ qbia,
    const float* __restrict__ vbia,
    unsigned short* __restrict__ xb, unsigned short* __restrict__ Wqkvb,
    unsigned short* __restrict__ Wpb, float* __restrict__ bias3)
{
    int i = blockIdx.x * 256 + threadIdx.x;
    if (i < 1048576) {
        *(bf16x8*)&xb[(long)i * 8] = pack8(&x[(long)i * 8]);
    } else if (i < 1441792) {
        int j = i - 1048576;
        *(bf16x8*)&Wqkvb[(long)j * 8] = pack8(&Wqkv[(long)j * 8]);
    } else if (i < 1572864) {
        int j = i - 1441792;
        *(bf16x8*)&Wpb[(long)j * 8] = pack8(&Wp[(long)j * 8]);
    } else if (i < 1573248) {
        int j = (i - 1572864) * 8;
        for (int u = 0; u < 8; ++u) {
            int n = j + u;
            float v = 0.0f;
            if (n < 1024) v = qbia[n];
            else if (n >= 2048) v = vbia[n - 2048];
            bias3[n] = v;
        }
    }
}

// ------------------------- GEMM, B^T input, 32x32x16 MFMA, global_load_lds
// R15: slot-XOR LDS swizzle (see file header). Staged chunk = 16 rows x 64B;
// within each row the 16B slot is XORed with (row>>1)&3 — applied on the
// global source (write side) and the fragment read (read side).
template<bool OUT_F32>
__global__ __launch_bounds__(256) void k_gemm_lds(
    const unsigned short* __restrict__ A, const unsigned short* __restrict__ Bh,
    const float* __restrict__ bias, void* __restrict__ Cp, int N, int K)
{
    __shared__ unsigned short As[128 * 32];
    __shared__ unsigned short Bs[128 * 32];
    const int t = threadIdx.x, wave = t >> 6, lane = t & 63;
    const int m32 = lane & 31, half = lane >> 5;
    const int bm = blockIdx.x * 128, bn = blockIdx.y * 128;
    const int wr = (wave >> 1) * 64, wc = (wave & 1) * 64;
    f32x16 acc[2][2] = {};

    const int srow = lane >> 2;        // 0..15
    // write-side swizzle: slot = (lane&3) ^ ((srow>>1)&3); (lane>>3)&3 == (srow>>1)&3
    const int scol = (((lane & 3) ^ ((lane >> 3) & 3))) * 8;
    const int c0 = wave * 2, c1 = wave * 2 + 1;
    const long ga0 = (long)(bm + c0 * 16 + srow) * K + scol;
    const long ga1 = (long)(bm + c1 * 16 + srow) * K + scol;
    const long gb0 = (long)(bn + c0 * 16 + srow) * K + scol;
    const long gb1 = (long)(bn + c1 * 16 + srow) * K + scol;

    // read-side swizzle term for this lane's fragment rows (row = ..+m32)
    const int swz = (m32 >> 1) & 3;

    for (int kt = 0; kt < K; kt += 32) {
        __syncthreads();
        gload_lds16(&A[ga0 + kt], &As[c0 * 512]);
        gload_lds16(&A[ga1 + kt], &As[c1 * 512]);
        gload_lds16(&Bh[gb0 + kt], &Bs[c0 * 512]);
        gload_lds16(&Bh[gb1 + kt], &Bs[c1 * 512]);
        __syncthreads();
        bf16x8 af[2][2], bfr[2][2];
        for (int mt = 0; mt < 2; ++mt)
            for (int f = 0; f < 2; ++f)
                af[mt][f] = *(const bf16x8*)&As[(wr + mt * 32 + m32) * 32 +
                                                (((f * 2 + half) ^ swz) * 8)];
        for (int nt = 0; nt < 2; ++nt)
            for (int f = 0; f < 2; ++f)
                bfr[nt][f] = *(const bf16x8*)&Bs[(wc + nt * 32 + m32) * 32 +
                                                 (((f * 2 + half) ^ swz) * 8)];
        for (int f = 0; f < 2; ++f)
            for (int mt = 0; mt < 2; ++mt)
                for (int nt = 0; nt < 2; ++nt)
                    acc[mt][nt] = __builtin_amdgcn_mfma_f32_32x32x16_bf16(
                        af[mt][f], bfr[nt][f], acc[mt][nt], 0, 0, 0);
    }
    // epilogue: 32x32 C/D layout col=lane&31, row=(r&3)+8*(r>>2)+4*half
    for (int mt = 0; mt < 2; ++mt)
        for (int nt = 0; nt < 2; ++nt) {
            int gn = bn + wc + nt * 32 + m32;
            float bv = bias[gn];
            for (int r = 0; r < 16; ++r) {
                int gm = bm + wr + mt * 32 + (r & 3) + 8 * (r >> 2) + 4 * half;
                float val = acc[mt][nt][r] + bv;
                if (OUT_F32) ((float*)Cp)[(long)gm * N + gn] = val;
                else ((unsigned short*)Cp)[(long)gm * N + gn] = f2bf(val);
            }
        }
}

// ------------------------- fused k L2-normalize + v transpose (one qkv pass)
__global__ __launch_bounds__(256) void k_prep_kv(
    const unsigned short* __restrict__ qkv, unsigned short* __restrict__ kb,
    unsigned short* __restrict__ vT)
{
    __shared__ unsigned short Vsh[64 * 72];
    const int t = threadIdx.x;
    const int bh = blockIdx.y, l0 = blockIdx.x * 64;
    const int h = bh & 15, b = bh >> 4;
    const int ll = t >> 2, c16 = (t & 3) * 16;
    const long rowbase = (long)(b * 2048 + l0 + ll) * 3072;

    {
        bf16x8 k0 = *(const bf16x8*)&qkv[rowbase + 1024 + h * 64 + c16];
        bf16x8 k1 = *(const bf16x8*)&qkv[rowbase + 1024 + h * 64 + c16 + 8];
        float e[16]; float ss = 0.f;
        for (int j = 0; j < 8; ++j) { e[j]     = bf2f((unsigned short)k0[j]); ss += e[j] * e[j]; }
        for (int j = 0; j < 8; ++j) { e[8 + j] = bf2f((unsigned short)k1[j]); ss += e[8 + j] * e[8 + j]; }
        ss += __shfl_xor(ss, 1, 64);
        ss += __shfl_xor(ss, 2, 64);
        float rs = 1.0f / fmaxf(sqrtf(ss), 1e-12f);
        bf16x8 o0, o1;
        for (int j = 0; j < 8; ++j) o0[j] = (short)f2bf(e[j] * rs);
        for (int j = 0; j < 8; ++j) o1[j] = (short)f2bf(e[8 + j] * rs);
        long dst = ((long)bh * 2048 + l0 + ll) * 64 + c16;
        *(bf16x8*)&kb[dst]     = o0;
        *(bf16x8*)&kb[dst + 8] = o1;
    }
    *(bf16x8*)&Vsh[ll * 72 + c16]     = *(const bf16x8*)&qkv[rowbase + 2048 + h * 64 + c16];
    *(bf16x8*)&Vsh[ll * 72 + c16 + 8] = *(const bf16x8*)&qkv[rowbase + 2048 + h * 64 + c16 + 8];
    __syncthreads();
    const int d = t >> 2, ls = (t & 3) * 16;
    unsigned short tmp[16];
    for (int j = 0; j < 16; ++j) tmp[j] = Vsh[(ls + j) * 72 + d];
    long dst = (long)(bh * 64 + d) * 2048 + l0 + ls;
    *(bf16x8*)&vT[dst]     = *(bf16x8*)&tmp[0];
    *(bf16x8*)&vT[dst + 8] = *(bf16x8*)&tmp[8];
}

// ------------------------------------------------------------ flash attention
// 32x32x16 MFMA, S^T form (key-permutation: P stays in registers).
// R14 (unchanged): 64 q-rows per wave (two 32-q groups A/B sharing K/V
// fragment regs). Barrier/staging skeleton from R12. Rowsum in lacc MFMAs.
__global__ __launch_bounds__(256, 2) void k_attn32(
    const unsigned short* __restrict__ qkv, const unsigned short* __restrict__ kb,
    const unsigned short* __restrict__ vT, const float* __restrict__ sml,
    unsigned short* __restrict__ attn)
{
    __shared__ unsigned short Ks[2][64 * 72];
    __shared__ unsigned short Vs[2][64 * 72];
    const int t = threadIdx.x, wave = t >> 6, lane = t & 63;
    const int m32 = lane & 31, half = lane >> 5;
    // XCD-chunked swizzle: 512 blocks, 64 logical per XCD = 8 (b,h) groups
    // (4MB K/V = L2 size). Proven lever (R10: FETCH 139MB -> 24.6MB).
    const int wg = blockIdx.x;
    const int logical = (wg & 7) * 64 + (wg >> 3);
    const int bh = logical >> 3, qblk = logical & 7;
    const int h = bh & 15, b = bh >> 4;
    const int q0 = qblk * 256 + wave * 64;     // rows q0..q0+31 (A), q0+32..q0+63 (B)
    const float scale = __expf(fminf(sml[h], MAXLOG));
    const float c2 = scale * LOG2E;   // shift for the (rare) large-scale path

    // permuted physical key row for the S^T A-frag (swap quads 1<->2, 5<->6)
    const int qd = m32 >> 2, lo = qd & 3;
    const int prow = ((((lo == 1) || (lo == 2)) ? (qd ^ 3) : qd) << 2) | (m32 & 3);

    // fused q load + L2-normalize for both q-groups; scale folded with LOG2E
    bf16x8 aqA[4], aqB[4];
    {
        long base = (long)(b * 2048 + q0 + m32) * 3072 + h * 64;
        float e[32]; float ss = 0.f;
        for (int f = 0; f < 4; ++f) {
            aqA[f] = *(const bf16x8*)&qkv[base + f * 16 + half * 8];
            for (int j = 0; j < 8; ++j) { float x = bf2f((unsigned short)aqA[f][j]); e[f * 8 + j] = x; ss += x * x; }
        }
        ss += __shfl_xor(ss, 32, 64);
        float rs = (scale * LOG2E) / fmaxf(sqrtf(ss), 1e-12f);
        for (int f = 0; f < 4; ++f)
            for (int j = 0; j < 8; ++j) aqA[f][j] = (short)f2bf(e[f * 8 + j] * rs);
    }
    {
        long base = (long)(b * 2048 + q0 + 32 + m32) * 3072 + h * 64;
        float e[32]; float ss = 0.f;
        for (int f = 0; f < 4; ++f) {
            aqB[f] = *(const bf16x8*)&qkv[base + f * 16 + half * 8];
            for (int j = 0; j < 8; ++j) { float x = bf2f((unsigned short)aqB[f][j]); e[f * 8 + j] = x; ss += x * x; }
        }
        ss += __shfl_xor(ss, 32, 64);
        float rs = (scale * LOG2E) / fmaxf(sqrtf(ss), 1e-12f);
        for (int f = 0; f < 4; ++f)
            for (int j = 0; j < 8; ++j) aqB[f][j] = (short)f2bf(e[f * 8 + j] * rs);
    }

    f32x16 oA0 = {}, oA1 = {}, lA = {};
    f32x16 oB0 = {}, oB1 = {}, lB = {};
    bf16x8 ones; for (int i = 0; i < 8; ++i) ones[i] = (short)0x3F80;
    const int sr = t >> 2, sc = (t & 3) * 16;
    const long kbase = (long)bh * 2048 * 64;
    const long vbase = (long)bh * 64 * 2048;

#define LOADT(kt) \
    kpA = *(const bf16x8*)&kb[kbase + (long)((kt) + sr) * 64 + sc];      \
    kpB = *(const bf16x8*)&kb[kbase + (long)((kt) + sr) * 64 + sc + 8];  \
    vpA = *(const bf16x8*)&vT[vbase + (long)sr * 2048 + (kt) + sc];      \
    vpB = *(const bf16x8*)&vT[vbase + (long)sr * 2048 + (kt) + sc + 8];

#define STORET(buf) \
    *(bf16x8*)&Ks[buf][sr * 72 + sc]     = kpA;  \
    *(bf16x8*)&Ks[buf][sr * 72 + sc + 8] = kpB;  \
    *(bf16x8*)&Vs[buf][sr * 72 + sc]     = vpA;  \
    *(bf16x8*)&Vs[buf][sr * 72 + sc + 8] = vpB;

// QK^T + exp2 + pack for one q-group (AQ) into two packed A-frags (AP0,AP1)
#define SCORE(AQ, AP0, AP1, KF0, KF1, KF2, KF3, SUB) \
    {                                                                                      \
        f32x16 s = {};                                                                     \
        s = __builtin_amdgcn_mfma_f32_32x32x16_bf16(KF0, AQ[0], s, 0, 0, 0);               \
        s = __builtin_amdgcn_mfma_f32_32x32x16_bf16(KF1, AQ[1], s, 0, 0, 0);               \
        s = __builtin_amdgcn_mfma_f32_32x32x16_bf16(KF2, AQ[2], s, 0, 0, 0);               \
        s = __builtin_amdgcn_mfma_f32_32x32x16_bf16(KF3, AQ[3], s, 0, 0, 0);               \
        unsigned pu[16];                                                                   \
        for (int j = 0; j < 16; ++j)                                                       \
            pu[j] = fbits(__builtin_amdgcn_exp2f(s[j] - (SUB)));                           \
        uint4 a0u, a1u;                                                                    \
        a0u.x = __builtin_amdgcn_perm(pu[1],  pu[0],  0x07060302u);                        \
        a0u.y = __builtin_amdgcn_perm(pu[3],  pu[2],  0x07060302u);                        \
        a0u.z = __builtin_amdgcn_perm(pu[5],  pu[4],  0x07060302u);                        \
        a0u.w = __builtin_amdgcn_perm(pu[7],  pu[6],  0x07060302u);                        \
        a1u.x = __builtin_amdgcn_perm(pu[9],  pu[8],  0x07060302u);                        \
        a1u.y = __builtin_amdgcn_perm(pu[11], pu[10], 0x07060302u);                        \
        a1u.z = __builtin_amdgcn_perm(pu[13], pu[12], 0x07060302u);                        \
        a1u.w = __builtin_amdgcn_perm(pu[15], pu[14], 0x07060302u);                        \
        __builtin_memcpy(&AP0, &a0u, 16); __builtin_memcpy(&AP1, &a1u, 16);                \
    }

#define ATTN_STEP(KS, VS, SUB) \
    for (int ktile = 0; ktile < 2; ++ktile) {                                              \
        const unsigned short* krow = &KS[(ktile * 32 + prow) * 72 + half * 8];             \
        bf16x8 kf0 = *(const bf16x8*)&krow[0];                                             \
        bf16x8 kf1 = *(const bf16x8*)&krow[16];                                            \
        bf16x8 kf2 = *(const bf16x8*)&krow[32];                                            \
        bf16x8 kf3 = *(const bf16x8*)&krow[48];                                            \
        bf16x8 apA0, apA1, apB0, apB1;                                                     \
        SCORE(aqA, apA0, apA1, kf0, kf1, kf2, kf3, SUB)                                    \
        SCORE(aqB, apB0, apB1, kf0, kf1, kf2, kf3, SUB)                                    \
        for (int c = 0; c < 2; ++c) {                                                      \
            bf16x8 aA = c ? apA1 : apA0;                                                   \
            bf16x8 aB = c ? apB1 : apB0;                                                   \
            bf16x8 bv0 = *(const bf16x8*)&VS[m32 * 72        + ktile * 32 + c * 16 + half * 8]; \
            bf16x8 bv1 = *(const bf16x8*)&VS[(32 + m32) * 72 + ktile * 32 + c * 16 + half * 8]; \
            oA0 = __builtin_amdgcn_mfma_f32_32x32x16_bf16(aA, bv0, oA0, 0, 0, 0);          \
            oA1 = __builtin_amdgcn_mfma_f32_32x32x16_bf16(aA, bv1, oA1, 0, 0, 0);          \
            lA  = __builtin_amdgcn_mfma_f32_32x32x16_bf16(aA, ones, lA, 0, 0, 0);          \
            oB0 = __builtin_amdgcn_mfma_f32_32x32x16_bf16(aB, bv0, oB0, 0, 0, 0);          \
            oB1 = __builtin_amdgcn_mfma_f32_32x32x16_bf16(aB, bv1, oB1, 0, 0, 0);          \
            lB  = __builtin_amdgcn_mfma_f32_32x32x16_bf16(aB, ones, lB, 0, 0, 0);          \
        }                                                                                  \
    }

#define KLOOP(SUB) \
    for (int kt = 0; kt < 2048; kt += 128) {                 \
        LOADT(kt + 64)                                       \
        ATTN_STEP(Ks[0], Vs[0], SUB)                         \
        STORET(1)                                            \
        __syncthreads();                                     \
        const bool more = (kt + 128) < 2048;                 \
        if (more) { LOADT(kt + 128) }                        \
        ATTN_STEP(Ks[1], Vs[1], SUB)                         \
        if (more) {                                          \
            STORET(0)                                        \
            __syncthreads();                                 \
        }                                                    \
    }

    bf16x8 kpA, kpB, vpA, vpB;
    LOADT(0)
    STORET(0)
    __syncthreads();

    if (c2 < 30.0f) {      // wave-uniform; scale=4 here => fast path
        KLOOP(0.0f)        // s - 0.0f folds away: no per-score VALU shift
    } else {
        KLOOP(c2)          // overflow-safe general path
    }
#undef LOADT
#undef STORET
#undef SCORE
#undef ATTN_STEP
#undef KLOOP

    // epilogue: divide by rowsum (lacc reg r matches o reg r), write attn[B,L,C]
    for (int r = 0; r < 16; ++r) {
        int m = (r & 3) + 8 * (r >> 2) + 4 * half;
        float invA = 1.0f / lA[r];
        long dstA = (long)(b * 2048 + q0 + m) * 1024 + h * 64;
        attn[dstA + m32]      = f2bf(oA0[r] * invA);
        attn[dstA + 32 + m32] = f2bf(oA1[r] * invA);
        float invB = 1.0f / lB[r];
        long dstB = (long)(b * 2048 + q0 + 32 + m) * 1024 + h * 64;
        attn[dstB + m32]      = f2bf(oB0[r] * invB);
        attn[dstB + 32 + m32] = f2bf(oB1[r] * invB);
    }
}

// ---------------------------------------------------------------------------
extern "C" void kernel_launch(void* const* d_in, const int* in_sizes, int n_in,
                              void* d_out, int out_size, void* d_ws, size_t ws_size,
                              hipStream_t stream) {
    const float* x    = (const float*)d_in[0];
    const float* Wqkv = (const float*)d_in[1];
    const float* qbia = (const float*)d_in[2];
    const float* vbia = (const float*)d_in[3];
    const float* sml  = (const float*)d_in[4];
    const float* Wp   = (const float*)d_in[5];
    const float* bp   = (const float*)d_in[6];

    char* ws = (char*)d_ws;
    unsigned short* qkv   = (unsigned short*)ws;                    // [0, 50.33MB)
    unsigned short* kbuf  = (unsigned short*)(ws + 50331648);       // hosts Wqkvb first
    unsigned short* Wqkvb = kbuf;
    unsigned short* vT    = (unsigned short*)(ws + 67108864);       // hosts xb first
    unsigned short* xb    = vT;
    unsigned short* attnb = (unsigned short*)(ws + 83886080);
    float*          bias3 = (float*)(ws + 100663296);               // 12KB
    unsigned short* Wpb   = (unsigned short*)(ws + 100679680);      // 2MB
    float*          out   = (float*)d_out;

    hipLaunchKernelGGL(k_prep, dim3(6146), dim3(256), 0, stream,
                       x, Wqkv, Wp, qbia, vbia, xb, Wqkvb, Wpb, bias3);
    hipLaunchKernelGGL((k_gemm_lds<false>), dim3(64, 24), dim3(256), 0, stream,
                       xb, Wqkvb, bias3, (void*)qkv, 3072, 1024);
    hipLaunchKernelGGL(k_prep_kv, dim3(32, 64), dim3(256), 0, stream, qkv, kbuf, vT);
    hipLaunchKernelGGL(k_attn32, dim3(512), dim3(256), 0, stream, qkv, kbuf, vT, sml, attnb);
    hipLaunchKernelGGL((k_gemm_lds<true>), dim3(64, 8), dim3(256), 0, stream,
                       attnb, Wpb, bp, (void*)out, 1024, 1024);
}